// Round 7
// baseline (513.517 us; speedup 1.0000x reference)
//
#include <hip/hip_runtime.h>
#include <math.h>

// Problem shape (fixed by setup_inputs)
#define BATCH 32
#define HH 768
#define WW 768
#define NBLK 2048   // 32 batches x 8 region-rows x 8 row-chunks

typedef float v4f __attribute__((ext_vector_type(4)));

// ws layout (bytes) — first 8704 bytes zeroed via hipMemsetAsync:
//   [0,256)    : 64 float sq buckets (atomicAdd accumulation)
//   [256,260)  : unsigned arrival counter
//   [512,8704) : 2048 float level-3 region diffs (atomicAdd accumulation)

__global__ __launch_bounds__(256) void fused_loss(
    const float* __restrict__ pred, const float* __restrict__ gt,
    const float* __restrict__ rgb, const float* __restrict__ th,
    float* __restrict__ out, float* __restrict__ ws)
{
    float* sqb = ws;                        // [64]
    unsigned* ctr = (unsigned*)(ws + 64);   // byte 256
    float* dreg = ws + 128;                 // [2048] at byte 512

    const int bid   = blockIdx.x;           // b*64 + ri*8 + chunk
    const int b     = bid >> 6;
    const int ri    = (bid >> 3) & 7;
    const int chunk = bid & 7;
    const size_t base = (size_t)b * (HH * WW) + (size_t)(ri * 96 + chunk * 12) * WW;

    const int t = threadIdx.x;
    const int g = t >> 5;                   // column stripe 0..7
    const int l = t & 31;

    const float* __restrict__ pb = pred + base + g * 96;
    const float* __restrict__ gb = gt   + base + g * 96;

    // stripe = 12 rows x 24 float4; lane l handles q = l + 32k, k=0..8
    int offs[9];
    #pragma unroll
    for (int k = 0; k < 9; ++k) {
        const int q   = l + 32 * k;         // 0..287
        const int row = q / 24;
        const int c   = q - row * 24;
        offs[k] = row * WW + c * 4;
    }
    v4f p[9], q4[9];
    #pragma unroll
    for (int k = 0; k < 9; ++k) p[k]  = *(const v4f*)(pb + offs[k]);
    #pragma unroll
    for (int k = 0; k < 9; ++k) q4[k] = *(const v4f*)(gb + offs[k]);

    float sq = 0.f, ds = 0.f;
    #pragma unroll
    for (int k = 0; k < 9; ++k) {
        const float dx = p[k][0] - q4[k][0];
        const float dy = p[k][1] - q4[k][1];
        const float dz = p[k][2] - q4[k][2];
        const float dw = p[k][3] - q4[k][3];
        sq += (dx * dx + dy * dy) + (dz * dz + dw * dw);
        ds += (dx + dy) + (dz + dw);
    }

    // ds: reduce within the 32-lane stripe group; sq: across the 64-lane wave
    #pragma unroll
    for (int o = 16; o > 0; o >>= 1) ds += __shfl_down(ds, o, 64);
    #pragma unroll
    for (int o = 32; o > 0; o >>= 1) sq += __shfl_down(sq, o, 64);

    if (l == 0)        atomicAdd(&dreg[((b << 3) + ri) * 8 + g], ds);
    if ((t & 63) == 0) atomicAdd(&sqb[bid & 63], sq);

    // ---- arrival: last block runs the tail ----
    __threadfence();
    __syncthreads();
    __shared__ unsigned s_last;
    if (t == 0) s_last = (atomicAdd(ctr, 1u) == (unsigned)(NBLK - 1)) ? 1u : 0u;
    __syncthreads();
    if (s_last == 0) return;
    __threadfence();

    // ---- tail: final loss (256 threads of the last block) ----
    __shared__ float d[2048];        // level-3 region diffs (b*64 + ri*8 + rj)
    __shared__ float d2[BATCH * 16];
    __shared__ float d1[BATCH * 4];
    __shared__ float redbuf[4 * 6];

    float s_sq = (t < 64) ? sqb[t] : 0.f;

    float l3 = 0.f;
    #pragma unroll
    for (int k = 0; k < 2; ++k) {
        const int i4 = t + 256 * k;          // float4 index, 512 total
        const v4f v = ((const v4f*)dreg)[i4];
        d[4 * i4 + 0] = v[0]; d[4 * i4 + 1] = v[1];
        d[4 * i4 + 2] = v[2]; d[4 * i4 + 3] = v[3];
        l3 += (fabsf(v[0]) + fabsf(v[1])) + (fabsf(v[2]) + fabsf(v[3]));
    }
    __syncthreads();

    // level 2: 32 batches x 16 cells, 2x2 aggregation of level-3
    float l2 = 0.f;
    #pragma unroll
    for (int k = 0; k < 2; ++k) {
        const int i = t + 256 * k;
        const int bb = i >> 4, r2 = i & 15;
        const int i2 = r2 >> 2, j2 = r2 & 3;
        const float* db = d + bb * 64;
        const float v = (db[(2 * i2) * 8 + 2 * j2]     + db[(2 * i2) * 8 + 2 * j2 + 1])
                      + (db[(2 * i2 + 1) * 8 + 2 * j2] + db[(2 * i2 + 1) * 8 + 2 * j2 + 1]);
        d2[i] = v;
        l2 += fabsf(v);
    }
    __syncthreads();

    // level 1: 32 x 4 cells
    float l1 = 0.f;
    if (t < BATCH * 4) {
        const int bb = t >> 2, r1 = t & 3;
        const int i1 = r1 >> 1, j1 = r1 & 1;
        const float* db = d2 + bb * 16;
        const float v = (db[(2 * i1) * 4 + 2 * j1]     + db[(2 * i1) * 4 + 2 * j1 + 1])
                      + (db[(2 * i1 + 1) * 4 + 2 * j1] + db[(2 * i1 + 1) * 4 + 2 * j1 + 1]);
        d1[t] = v;
        l1 = fabsf(v);
    }
    __syncthreads();

    // per-batch count diff + domain CE
    float cnt = 0.f, dom = 0.f;
    if (t < BATCH) {
        const float c = (d1[t * 4] + d1[t * 4 + 1]) + (d1[t * 4 + 2] + d1[t * 4 + 3]);
        cnt = fabsf(c);
        const float x0 = rgb[t * 2], x1 = rgb[t * 2 + 1];
        const float mx = fmaxf(x0, x1);
        dom  = (mx + logf(expf(x0 - mx) + expf(x1 - mx))) - x0;
        const float y0 = th[t * 2], y1 = th[t * 2 + 1];
        const float my = fmaxf(y0, y1);
        dom += (my + logf(expf(y0 - my) + expf(y1 - my))) - y1;
    }

    // fused 6-value reduction: wave shuffle, then 4-wave LDS combine
    float vals[6] = {s_sq, l3, l2, l1, cnt, dom};
    #pragma unroll
    for (int off = 32; off > 0; off >>= 1) {
        #pragma unroll
        for (int j = 0; j < 6; ++j) vals[j] += __shfl_down(vals[j], off, 64);
    }
    const int wave = t >> 6;
    if ((t & 63) == 0) {
        #pragma unroll
        for (int j = 0; j < 6; ++j) redbuf[wave * 6 + j] = vals[j];
    }
    __syncthreads();
    if (t == 0) {
        float S[6];
        #pragma unroll
        for (int j = 0; j < 6; ++j)
            S[j] = (redbuf[j] + redbuf[6 + j]) + (redbuf[12 + j] + redbuf[18 + j]);
        const float density  = S[0] / (float)((size_t)BATCH * HH * WW);
        const float count_l  = S[4] / (float)BATCH;
        const float regional = ((S[3] + S[2] + S[1]) / (float)BATCH) / 192.0f;
        const float domain   = S[5] / 64.0f;
        out[0] = 100.0f * density + 0.001f * count_l + 1.0f * regional + 0.5f * domain;
    }
}

extern "C" void kernel_launch(void* const* d_in, const int* in_sizes, int n_in,
                              void* d_out, int out_size, void* d_ws, size_t ws_size,
                              hipStream_t stream) {
    const float* pred = (const float*)d_in[0];
    const float* gt   = (const float*)d_in[1];
    const float* rgb  = (const float*)d_in[2];
    const float* th   = (const float*)d_in[3];
    float* out = (float*)d_out;
    float* ws  = (float*)d_ws;

    // zero the accumulators + arrival counter (ws is poisoned 0xAA pre-launch)
    (void)hipMemsetAsync(d_ws, 0, 8704, stream);
    fused_loss<<<NBLK, 256, 0, stream>>>(pred, gt, rgb, th, out, ws);
}

// Round 8
// 171.097 us; speedup vs baseline: 3.0013x; 3.0013x over previous
//
#include <hip/hip_runtime.h>
#include <math.h>

// Problem shape (fixed by setup_inputs)
#define BATCH 32
#define HH 768
#define WW 768
#define NBLK 2048   // 32 batches x 8 region-rows x 8 row-chunks

typedef float v4f __attribute__((ext_vector_type(4)));

// ---------------------------------------------------------------------------
// Kernel 1: block = (b, ri, chunk) covering 12 contiguous full-width rows
// (2304 float4 per array). PERFECTLY LINEAR wave access: lane reads float4
// index 256*k + t, so each wave64 load covers one contiguous 1KB span
// (m13-copy pattern). Region (column-stripe) membership is k-periodic mod 3:
// stripe(f) = ((t%192) + 64*(k%3)) % 192 / 24 -> 3 static accumulators/lane,
// deposited via 3 LDS atomics after the loop.
// ---------------------------------------------------------------------------
__global__ __launch_bounds__(256) void region_reduce(
    const float* __restrict__ pred, const float* __restrict__ gt,
    float* __restrict__ sq_out, float* __restrict__ dws)
{
    const int bid   = blockIdx.x;        // b*64 + ri*8 + chunk
    const int b     = bid >> 6;
    const int ri    = (bid >> 3) & 7;
    const int chunk = bid & 7;
    const size_t base = (size_t)b * (HH * WW) + (size_t)(ri * 96 + chunk * 12) * WW;

    const int t = threadIdx.x;
    const float* __restrict__ pb = pred + base;
    const float* __restrict__ gb = gt   + base;

    // stripe ids for the 3 k-phases (j = k % 3)
    const int t192 = t % 192;
    int stripe[3];
    #pragma unroll
    for (int j = 0; j < 3; ++j) stripe[j] = ((t192 + 64 * j) % 192) / 24;

    float sq = 0.f;
    float a0 = 0.f, a1 = 0.f, a2 = 0.f;   // ds accumulators per k-phase

    #pragma unroll
    for (int k = 0; k < 9; ++k) {
        const int f = 256 * k + t;        // float4 index, contiguous per wave
        const v4f p = *(const v4f*)(pb + 4 * f);
        const v4f g = *(const v4f*)(gb + 4 * f);
        const float dx = p[0] - g[0], dy = p[1] - g[1];
        const float dz = p[2] - g[2], dw = p[3] - g[3];
        sq += (dx * dx + dy * dy) + (dz * dz + dw * dw);
        const float d = (dx + dy) + (dz + dw);
        if (k % 3 == 0) a0 += d;
        else if (k % 3 == 1) a1 += d;
        else a2 += d;
    }

    // stripe sums via LDS atomics (ds_add_f32), 3 per thread
    __shared__ float sstripe[8];
    __shared__ float lsq[4];
    if (t < 8) sstripe[t] = 0.f;
    __syncthreads();
    atomicAdd(&sstripe[stripe[0]], a0);
    atomicAdd(&sstripe[stripe[1]], a1);
    atomicAdd(&sstripe[stripe[2]], a2);

    // sq: wave shuffle then LDS combine
    #pragma unroll
    for (int o = 32; o > 0; o >>= 1) sq += __shfl_down(sq, o, 64);
    if ((t & 63) == 0) lsq[t >> 6] = sq;
    __syncthreads();

    if (t < 8) {
        const int r = ((b << 3) + ri) * 8 + t;   // region id
        dws[r * 8 + chunk] = sstripe[t];
    }
    if (t == 0) sq_out[bid] = (lsq[0] + lsq[1]) + (lsq[2] + lsq[3]);
}

// ---------------------------------------------------------------------------
// Kernel 2: single block. Aggregates chunk partials -> level-3 regions,
// builds levels 2/1, count loss, domain CE, final weighted sum.
// ---------------------------------------------------------------------------
__global__ __launch_bounds__(256) void finalize(
    const float* __restrict__ sq, const float* __restrict__ dws,
    const float* __restrict__ rgb, const float* __restrict__ th,
    float* __restrict__ out)
{
    __shared__ float d[2048];        // level-3 region diffs (b*64 + ri*8 + rj)
    __shared__ float d2[BATCH * 16];
    __shared__ float d1[BATCH * 4];
    __shared__ float redbuf[4 * 6];
    const int t = threadIdx.x;

    // density partials (2048 floats as 512 float4)
    float s_sq = 0.f;
    #pragma unroll
    for (int k = 0; k < 2; ++k) {
        const v4f v = ((const v4f*)sq)[t + 256 * k];
        s_sq += (v[0] + v[1]) + (v[2] + v[3]);
    }

    // level-3 region diffs: sum 8 chunk partials each (two float4)
    float l3 = 0.f;
    #pragma unroll
    for (int k = 0; k < 8; ++k) {
        const int r = t + 256 * k;
        const v4f a = ((const v4f*)(dws + r * 8))[0];
        const v4f bb = ((const v4f*)(dws + r * 8))[1];
        const float v = ((a[0] + a[1]) + (a[2] + a[3]))
                      + ((bb[0] + bb[1]) + (bb[2] + bb[3]));
        d[r] = v;
        l3 += fabsf(v);
    }
    __syncthreads();

    // level 2: 32 batches x 16 cells, 2x2 aggregation of level-3
    float l2 = 0.f;
    #pragma unroll
    for (int k = 0; k < 2; ++k) {
        const int i = t + 256 * k;
        const int bb = i >> 4, r2 = i & 15;
        const int i2 = r2 >> 2, j2 = r2 & 3;
        const float* db = d + bb * 64;
        const float v = (db[(2 * i2) * 8 + 2 * j2]     + db[(2 * i2) * 8 + 2 * j2 + 1])
                      + (db[(2 * i2 + 1) * 8 + 2 * j2] + db[(2 * i2 + 1) * 8 + 2 * j2 + 1]);
        d2[i] = v;
        l2 += fabsf(v);
    }
    __syncthreads();

    // level 1: 32 x 4 cells
    float l1 = 0.f;
    if (t < BATCH * 4) {
        const int bb = t >> 2, r1 = t & 3;
        const int i1 = r1 >> 1, j1 = r1 & 1;
        const float* db = d2 + bb * 16;
        const float v = (db[(2 * i1) * 4 + 2 * j1]     + db[(2 * i1) * 4 + 2 * j1 + 1])
                      + (db[(2 * i1 + 1) * 4 + 2 * j1] + db[(2 * i1 + 1) * 4 + 2 * j1 + 1]);
        d1[t] = v;
        l1 = fabsf(v);
    }
    __syncthreads();

    // per-batch count diff + domain CE
    float cnt = 0.f, dom = 0.f;
    if (t < BATCH) {
        const float c = (d1[t * 4] + d1[t * 4 + 1]) + (d1[t * 4 + 2] + d1[t * 4 + 3]);
        cnt = fabsf(c);
        const float x0 = rgb[t * 2], x1 = rgb[t * 2 + 1];
        const float mx = fmaxf(x0, x1);
        dom  = (mx + logf(expf(x0 - mx) + expf(x1 - mx))) - x0;
        const float y0 = th[t * 2], y1 = th[t * 2 + 1];
        const float my = fmaxf(y0, y1);
        dom += (my + logf(expf(y0 - my) + expf(y1 - my))) - y1;
    }

    // fused 6-value reduction: wave shuffle, then 4-wave LDS combine
    float vals[6] = {s_sq, l3, l2, l1, cnt, dom};
    #pragma unroll
    for (int off = 32; off > 0; off >>= 1) {
        #pragma unroll
        for (int j = 0; j < 6; ++j) vals[j] += __shfl_down(vals[j], off, 64);
    }
    const int wave = t >> 6;
    if ((t & 63) == 0) {
        #pragma unroll
        for (int j = 0; j < 6; ++j) redbuf[wave * 6 + j] = vals[j];
    }
    __syncthreads();
    if (t == 0) {
        float S[6];
        #pragma unroll
        for (int j = 0; j < 6; ++j)
            S[j] = (redbuf[j] + redbuf[6 + j]) + (redbuf[12 + j] + redbuf[18 + j]);
        const float density  = S[0] / (float)((size_t)BATCH * HH * WW);
        const float count_l  = S[4] / (float)BATCH;
        const float regional = ((S[3] + S[2] + S[1]) / (float)BATCH) / 192.0f;
        const float domain   = S[5] / 64.0f;
        out[0] = 100.0f * density + 0.001f * count_l + 1.0f * regional + 0.5f * domain;
    }
}

extern "C" void kernel_launch(void* const* d_in, const int* in_sizes, int n_in,
                              void* d_out, int out_size, void* d_ws, size_t ws_size,
                              hipStream_t stream) {
    const float* pred = (const float*)d_in[0];
    const float* gt   = (const float*)d_in[1];
    const float* rgb  = (const float*)d_in[2];
    const float* th   = (const float*)d_in[3];
    float* out = (float*)d_out;

    float* sq  = (float*)d_ws;         // [2048] per-block sq partials
    float* dws = sq + NBLK;            // [2048 * 8] chunk partials

    region_reduce<<<NBLK, 256, 0, stream>>>(pred, gt, sq, dws);
    finalize<<<1, 256, 0, stream>>>(sq, dws, rgb, th, out);
}